// Round 1
// baseline (61.661 us; speedup 1.0000x reference)
//
#include <hip/hip_runtime.h>
#include <math.h>

// QuantumLayer: 18-qubit, 2-layer RY+CNOT-chain circuit, Z expectations.
//
// Analytic reduction (see derivation in session notes):
//   - CNOT chain C maps |x> -> |y>, y_q = x_0^...^x_q (prefix XOR), so
//     <Z_q> after the final chain = <Z_0...Z_q> before it.
//   - C * R1 |0> has amplitude prod_q g_q(y_{q-1}^y_q): a bond-dim-2 MPS.
//   - Layer-2 RYs are single-site ops; expectation of the parity string is a
//     product of 4x4 transfer matrices over the doubled bond (l,l'):
//       E_q^O[(l,l'),(r,r')] = (U^T O U)[r,r'] * g_q(l^r) * g_q(l'^r')
//     with U^T Z U = [[cos t2, -sin t2],[-sin t2, -cos t2]]  (t2 = full angle)
//     and  U^T I U = I  (so E^I only needs the diagonal of its input).
//   out[b][q] = e00^T (prod_{j<=q} E_j^Z) (prod_{j>q} E_j^I) ones4.

#define NQ 18

__global__ __launch_bounds__(64) void qmps_kernel(const float* __restrict__ in,
                                                  float* __restrict__ out,
                                                  int batch) {
    int b = blockIdx.x * blockDim.x + threadIdx.x;
    if (b >= batch) return;

    const float* ang = in + b * (2 * NQ);

    // Layer-1 half-angle cos/sin (the MPS "g" functions) and
    // layer-2 full-angle cos/sin (the W = U^T Z U entries).
    float c1[NQ], s1[NQ], cw[NQ], sw[NQ];
#pragma unroll
    for (int q = 0; q < NQ; ++q) {
        float h1 = 0.5f * ang[q];
        c1[q] = cosf(h1);
        s1[q] = sinf(h1);
        float t2 = ang[NQ + q];
        cw[q] = cosf(t2);
        sw[q] = sinf(t2);
    }

    // Suffix sweep with identity transfers: Rv[k] = E_k^I * Rv[k+1], Rv[18]=ones.
    // E^I[(l,l'),(r,r')] = delta_{r,r'} g(l^r) g(l'^r)  -> uses only diag of input.
    // Component order: 0:(0,0) 1:(0,1) 2:(1,0) 3:(1,1).
    float Rv[NQ + 1][4];
    Rv[NQ][0] = 1.0f; Rv[NQ][1] = 1.0f; Rv[NQ][2] = 1.0f; Rv[NQ][3] = 1.0f;
#pragma unroll
    for (int k = NQ - 1; k >= 1; --k) {
        float c = c1[k], s = s1[k];
        float d0 = Rv[k + 1][0], d3 = Rv[k + 1][3];
        float cc = c * c, ss = s * s, cs = c * s;
        Rv[k][0] = cc * d0 + ss * d3;
        Rv[k][1] = cs * (d0 + d3);
        Rv[k][2] = Rv[k][1];
        Rv[k][3] = ss * d0 + cc * d3;
    }

    // Prefix sweep with Z transfers, starting from e00 (left boundary l=l'=0).
    // L' = W .* (G L G), G = [[c,s],[s,c]] (g(l^r)), W = [[cw,-sw],[-sw,-cw]].
    float L00 = 1.0f, L01 = 0.0f, L10 = 0.0f, L11 = 0.0f;
#pragma unroll
    for (int q = 0; q < NQ; ++q) {
        float c = c1[q], s = s1[q];
        float GL00 = c * L00 + s * L10;
        float GL01 = c * L01 + s * L11;
        float GL10 = s * L00 + c * L10;
        float GL11 = s * L01 + c * L11;
        float A00 = GL00 * c + GL01 * s;
        float A01 = GL00 * s + GL01 * c;
        float A10 = GL10 * c + GL11 * s;
        float A11 = GL10 * s + GL11 * c;
        L00 =  cw[q] * A00;
        L01 = -sw[q] * A01;
        L10 = -sw[q] * A10;
        L11 = -cw[q] * A11;
        // Close with the identity-suffix vector Rv[q+1] (Rv[18] = ones).
        out[b * NQ + q] = L00 * Rv[q + 1][0] + L01 * Rv[q + 1][1] +
                          L10 * Rv[q + 1][2] + L11 * Rv[q + 1][3];
    }
}

extern "C" void kernel_launch(void* const* d_in, const int* in_sizes, int n_in,
                              void* d_out, int out_size, void* d_ws, size_t ws_size,
                              hipStream_t stream) {
    const float* in = (const float*)d_in[0];
    float* out = (float*)d_out;
    int batch = in_sizes[0] / (2 * NQ);  // (BATCH, Q_LAYERS=2, NQ=18) float32
    dim3 grid((batch + 63) / 64);
    hipLaunchKernelGGL(qmps_kernel, grid, dim3(64), 0, stream, in, out, batch);
}